// Round 5
// baseline (611.925 us; speedup 1.0000x reference)
//
#include <hip/hip_runtime.h>
#include <hip/hip_bf16.h>

typedef _Float16 f16x8 __attribute__((ext_vector_type(8)));
typedef _Float16 f16x4 __attribute__((ext_vector_type(4)));
typedef float    f32x4 __attribute__((ext_vector_type(4)));

#define HW   36864   // 192*192
#define W_   192
#define NS   9216    // 96*96 patches
#define CCH  128     // channels (QK inner dim)
#define DV   512     // c*r*r  (PV output dim)
#define ROWS 64      // query rows per block
#define KV   64      // keys per tile
#define NT   144     // total key tiles
#define PROW 72      // padded P row stride (f16)

__device__ __forceinline__ void gload_lds16(const _Float16* src, _Float16* dst) {
    __builtin_amdgcn_global_load_lds(
        (const __attribute__((address_space(1))) void*)src,
        (__attribute__((address_space(3))) void*)dst, 16, 0, 0);
}

// ---------- prep: Vt[d][m] (f16, transposed patches) + F16[m][c] (f16 feat) ----------
__global__ __launch_bounds__(256) void prep_vt_kernel(const float* __restrict__ x,
        _Float16* __restrict__ Vt, _Float16* __restrict__ F16)
{
    int m = blockIdx.x * 256 + threadIdx.x;   // 0..9215
    int d = blockIdx.y;                       // 0..511
    int c = d >> 2, di = (d >> 1) & 1, dj = d & 1;
    int i = m / 96, j = m - i * 96;
    float v = x[c * HW + (2 * i + di) * W_ + (2 * j + dj)];
    _Float16 h = (_Float16)v;
    Vt[(size_t)d * NS + m] = h;
    if ((d & 3) == 0) F16[m * CCH + c] = h;   // di=dj=0 element == feat
}

// ---------- prep: csv[m] = valid ? 10/(||f_m||+eps) : 0 ----------
__global__ __launch_bounds__(64) void prep_csv_kernel(const _Float16* __restrict__ F16,
        const float* __restrict__ mask, float* __restrict__ csv)
{
    int m = blockIdx.x;
    int t = threadIdx.x;                      // one wave
    float a = (float)F16[m * CCH + 2 * t];
    float b = (float)F16[m * CCH + 2 * t + 1];
    float ss = a * a + b * b;
    #pragma unroll
    for (int off = 1; off <= 32; off <<= 1)
        ss += __shfl_xor(ss, off);
    if (t == 0) {
        int i = m / 96, j = m - i * 96;
        float ms = mask[(2 * i) * W_ + 2 * j];
        csv[m] = (ms == 0.0f) ? 10.0f / (sqrtf(ss) + 1e-8f) : 0.0f;
    }
}

// ---------- fused masked attention: producer/consumer wave specialization ----------
// 8 waves: 0-3 producers (QK+softmax+P, 16 rows each), 4-7 consumers (PV, 64 d each).
// Swapped QK: s = mfma(K, Q) -> lane owns query=c16, keys cf*16+g*4+r (packed b64 P writes).
template<int KT>
__global__ __launch_bounds__(512, 4) void flash_kernel(const _Float16* __restrict__ F16,
        const _Float16* __restrict__ Vt, const float* __restrict__ csv,
        _Float16* __restrict__ po, float* __restrict__ av)
{
    __shared__ __align__(16) _Float16 Kb[2][KV * CCH];    // 2 x 16 KB, src-preswizzled chunks
    __shared__ __align__(16) _Float16 Pb[2][ROWS * PROW]; // 2 x 9 KB, padded rows
    __shared__ __align__(16) float    abuf[2][ROWS];      // per-tile O-rescale factors
    __shared__ __align__(16) float    lbuf[ROWS];         // final 1/l

    const int tid  = threadIdx.x;
    const int wv   = tid >> 6;
    const int lane = tid & 63;
    const int g    = lane >> 4, c16 = lane & 15;
    const int n0   = (blockIdx.x >> 1) * ROWS;
    const int d0   = (blockIdx.x & 1) * 256;
    const int sp   = blockIdx.y;
    const int t0   = sp * KT;
    const bool prod = (wv < 4);
    const int cw   = wv & 3;   // producer rowgroup / consumer d-slice

    // consumer: stage 4 KB of K tile t into Kb[buf] via global_load_lds (src-preswizzled)
    auto stageK = [&](int buf, int t) {
        #pragma unroll
        for (int j = 0; j < 4; ++j) {
            const int keyb = cw * 16 + j * 4;
            const int key  = keyb + g;
            const int sc   = (c16 & 8) | ((c16 & 7) ^ (key & 7));
            gload_lds16(F16 + (size_t)(t * KV + key) * CCH + sc * 8,
                        &Kb[buf][keyb * CCH]);
        }
    };

    // producer state
    f16x8 q[4];
    float m_run = -1e30f, l_run = 0.0f;
    if (prod) {
        #pragma unroll
        for (int kk = 0; kk < 4; ++kk)
            q[kk] = *(const f16x8*)(F16 + (n0 + cw * 16 + c16) * CCH + kk * 32 + g * 8);
    }
    // consumer state
    f32x4 o[4][4];
    #pragma unroll
    for (int rf = 0; rf < 4; ++rf)
        #pragma unroll
        for (int df = 0; df < 4; ++df) o[rf][df] = 0.0f;

    // consumer: consume producer tile tp (P/abuf in Pb/abuf[tp&1])
    auto consume = [&](int tp) {
        const int pb = tp & 1;
        const int m0 = (t0 + tp) * KV;
        #pragma unroll
        for (int rf = 0; rf < 4; ++rf) {
            f32x4 a4 = *(const f32x4*)(&abuf[pb][rf * 16 + g * 4]);
            #pragma unroll
            for (int df = 0; df < 4; ++df)
                #pragma unroll
                for (int r = 0; r < 4; ++r) o[rf][df][r] *= a4[r];
        }
        #pragma unroll
        for (int kf = 0; kf < 2; ++kf) {
            f16x8 vr[4];
            #pragma unroll
            for (int df = 0; df < 4; ++df)
                vr[df] = *(const f16x8*)(Vt + (size_t)(d0 + cw * 64 + df * 16 + c16) * NS
                                         + m0 + kf * 32 + g * 8);
            f16x8 pa[4];
            #pragma unroll
            for (int rf = 0; rf < 4; ++rf)
                pa[rf] = *(const f16x8*)(&Pb[pb][(rf * 16 + c16) * PROW + kf * 32 + g * 8]);
            #pragma unroll
            for (int df = 0; df < 4; ++df)
                #pragma unroll
                for (int rf = 0; rf < 4; ++rf)
                    o[rf][df] = __builtin_amdgcn_mfma_f32_16x16x32_f16(
                                    pa[rf], vr[df], o[rf][df], 0, 0, 0);
        }
    };

    if (!prod) stageK(0, t0);
    __syncthreads();

    for (int tl = 0; tl < KT; ++tl) {
        const int buf = tl & 1;
        if (prod) {
            const int m0 = (t0 + tl) * KV;
            // ---- QK^T (swapped: A=K, B=Q) from swizzled Kb ----
            f32x4 s[4];
            #pragma unroll
            for (int cf = 0; cf < 4; ++cf) s[cf] = 0.0f;
            const int sw = c16 & 7;
            #pragma unroll
            for (int cf = 0; cf < 4; ++cf) {
                const _Float16* kr = &Kb[buf][(cf * 16 + c16) * CCH];
                #pragma unroll
                for (int kk = 0; kk < 4; ++kk) {
                    const int ch  = kk * 4 + g;
                    const int sch = (ch & 8) | ((ch & 7) ^ sw);
                    s[cf] = __builtin_amdgcn_mfma_f32_16x16x32_f16(
                                *(const f16x8*)(kr + sch * 8), q[kk], s[cf], 0, 0, 0);
                }
            }
            // ---- softmax: lane owns query c16; keys cf*16+g*4+r ----
            f32x4 cs4[4];
            #pragma unroll
            for (int cf = 0; cf < 4; ++cf)
                cs4[cf] = *(const f32x4*)(csv + m0 + cf * 16 + g * 4);
            float sv[4][4], tm = -1e30f;
            #pragma unroll
            for (int cf = 0; cf < 4; ++cf)
                #pragma unroll
                for (int r = 0; r < 4; ++r) {
                    float c = cs4[cf][r];
                    float v = (c > 0.0f) ? s[cf][r] * c : -1e30f;
                    sv[cf][r] = v;
                    tm = fmaxf(tm, v);
                }
            tm = fmaxf(tm, __shfl_xor(tm, 16));
            tm = fmaxf(tm, __shfl_xor(tm, 32));
            float al = 1.0f;
            if (__any(tm > m_run + 8.0f)) {
                float nm = fmaxf(m_run, tm);
                al = __expf(m_run - nm);
                l_run *= al; m_run = nm;
            }
            if (g == 0) abuf[buf][cw * 16 + c16] = al;
            float ps = 0.0f;
            #pragma unroll
            for (int cf = 0; cf < 4; ++cf) {
                f16x4 ph;
                #pragma unroll
                for (int r = 0; r < 4; ++r) {
                    float c = cs4[cf][r];
                    float e = (c > 0.0f) ? __expf(sv[cf][r] - m_run) : 0.0f;
                    ps += e;
                    ph[r] = (_Float16)e;
                }
                *(f16x4*)(&Pb[buf][(cw * 16 + c16) * PROW + cf * 16 + g * 4]) = ph;
            }
            ps += __shfl_xor(ps, 16);
            ps += __shfl_xor(ps, 32);
            l_run += ps;
        } else {
            if (tl + 1 < KT) stageK((tl + 1) & 1, t0 + tl + 1);
            if (tl > 0) consume(tl - 1);
        }
        __syncthreads();
    }

    // epilogue
    if (prod && g == 0) {
        lbuf[cw * 16 + c16] = (l_run > 0.0f) ? 1.0f / l_run : 0.0f;
        if (d0 == 0)
            av[sp * NS + n0 + cw * 16 + c16] =
                (l_run > 0.0f) ? m_run + __logf(l_run) : -1e30f;
    }
    __syncthreads();
    if (!prod) {
        consume(KT - 1);
        #pragma unroll
        for (int rf = 0; rf < 4; ++rf) {
            f32x4 li = *(const f32x4*)(&lbuf[rf * 16 + g * 4]);
            #pragma unroll
            for (int df = 0; df < 4; ++df) {
                f16x4 res;
                #pragma unroll
                for (int r = 0; r < 4; ++r) res[r] = (_Float16)(o[rf][df][r] * li[r]);
                *(f16x4*)(po + ((size_t)sp * DV + d0 + cw * 64 + df * 16 + c16) * NS
                              + n0 + rf * 16 + g * 4) = res;
            }
        }
    }
}

// ---------- final: merge splits (logsumexp weights) + mask blend ----------
template<int S>
__global__ __launch_bounds__(192) void combine_kernel(const float* __restrict__ x,
        const float* __restrict__ mask, const _Float16* __restrict__ po,
        const float* __restrict__ av, float* __restrict__ out)
{
    int i = blockIdx.x;      // 0..95
    int c = blockIdx.y;      // 0..127
    int w = threadIdx.x;     // 0..191
    int n = i * 96 + (w >> 1);

    float A = -1e30f;
    #pragma unroll
    for (int s = 0; s < S; ++s) A = fmaxf(A, av[s * NS + n]);
    float wt[S], wsum = 0.0f;
    #pragma unroll
    for (int s = 0; s < S; ++s) {
        float a = av[s * NS + n];
        float e = (a > -1e29f) ? __expf(a - A) : 0.0f;
        wt[s] = e; wsum += e;
    }
    float invw = (wsum > 0.0f) ? 1.0f / wsum : 0.0f;

    #pragma unroll
    for (int di = 0; di < 2; ++di) {
        int h = 2 * i + di;
        int d = c * 4 + di * 2 + (w & 1);
        float rv = 0.0f;
        #pragma unroll
        for (int s = 0; s < S; ++s)
            rv += wt[s] * (float)po[((size_t)s * DV + d) * NS + n];
        rv *= invw;
        float xv = x[c * HW + h * W_ + w];
        float mv = mask[h * W_ + w];
        out[c * HW + h * W_ + w] = xv * (1.0f - mv) + rv * mv;
    }
}

extern "C" void kernel_launch(void* const* d_in, const int* in_sizes, int n_in,
                              void* d_out, int out_size, void* d_ws, size_t ws_size,
                              hipStream_t stream) {
    const float* x    = (const float*)d_in[0];
    const float* mask = (const float*)d_in[1];
    float* out = (float*)d_out;

    char* ws = (char*)d_ws;
    _Float16* Vt  = (_Float16*)(ws);                     //  9,437,184 B
    _Float16* F16 = (_Float16*)(ws + 9437184);           //  2,359,296 B
    float*    csv = (float*)   (ws + 11796480);          //     36,864 B
    float*    av  = (float*)   (ws + 11833344);          //    294,912 B
    _Float16* po  = (_Float16*)(ws + 12128256);          //  SPL * 9,437,184 B

    prep_vt_kernel <<<dim3(36, 512), 256, 0, stream>>>(x, Vt, F16);
    prep_csv_kernel<<<NS, 64, 0, stream>>>(F16, mask, csv);

    const size_t base = 12128256ull;
    if (ws_size >= base + 8ull * 9437184ull) {
        flash_kernel<18><<<dim3(288, 8), 512, 0, stream>>>(F16, Vt, csv, po, av);
        combine_kernel<8><<<dim3(96, 128), 192, 0, stream>>>(x, mask, po, av, out);
    } else {
        flash_kernel<36><<<dim3(288, 4), 512, 0, stream>>>(F16, Vt, csv, po, av);
        combine_kernel<4><<<dim3(96, 128), 192, 0, stream>>>(x, mask, po, av, out);
    }
}

// Round 6
// 352.339 us; speedup vs baseline: 1.7368x; 1.7368x over previous
//
#include <hip/hip_runtime.h>
#include <hip/hip_bf16.h>

typedef _Float16 f16x8 __attribute__((ext_vector_type(8)));
typedef _Float16 f16x4 __attribute__((ext_vector_type(4)));
typedef float    f32x4 __attribute__((ext_vector_type(4)));

#define HW   36864   // 192*192
#define W_   192
#define NS   9216    // 96*96 patches
#define CCH  128     // channels (QK inner dim)
#define DV   512     // c*r*r  (PV output dim)
#define ROWS 64      // query rows per block
#define KV   64      // keys per tile
#define NT   144     // total key tiles

// ---------- prep: Vt[d][m] (f16, transposed patches) + F16[m][c] (f16 feat) ----------
__global__ __launch_bounds__(256) void prep_vt_kernel(const float* __restrict__ x,
        _Float16* __restrict__ Vt, _Float16* __restrict__ F16)
{
    int m = blockIdx.x * 256 + threadIdx.x;   // 0..9215
    int d = blockIdx.y;                       // 0..511
    int c = d >> 2, di = (d >> 1) & 1, dj = d & 1;
    int i = m / 96, j = m - i * 96;
    float v = x[c * HW + (2 * i + di) * W_ + (2 * j + dj)];
    _Float16 h = (_Float16)v;
    Vt[(size_t)d * NS + m] = h;
    if ((d & 3) == 0) F16[m * CCH + c] = h;   // di=dj=0 element == feat
}

// ---------- prep: csv[m] = valid ? 10/(||f_m||+eps) : 0 ----------
__global__ __launch_bounds__(64) void prep_csv_kernel(const _Float16* __restrict__ F16,
        const float* __restrict__ mask, float* __restrict__ csv)
{
    int m = blockIdx.x;
    int t = threadIdx.x;                      // one wave
    float a = (float)F16[m * CCH + 2 * t];
    float b = (float)F16[m * CCH + 2 * t + 1];
    float ss = a * a + b * b;
    #pragma unroll
    for (int off = 1; off <= 32; off <<= 1)
        ss += __shfl_xor(ss, off);
    if (t == 0) {
        int i = m / 96, j = m - i * 96;
        float ms = mask[(2 * i) * W_ + 2 * j];
        csv[m] = (ms == 0.0f) ? 10.0f / (sqrtf(ss) + 1e-8f) : 0.0f;
    }
}

// ---------- fused masked attention: 64 rows x full 512 d, 8 waves ----------
// Wave wv = (h = wv>>2, rg = wv&3). QK role: rowgroup rg x key-half h (swapped mfma(K,Q):
// lane owns query c16, keys h*32+cf*16+g*4+r). PV role: d-slice wv*64, all 64 rows.
// Single-buffer K (16KB) + P (8KB), 2 barriers/tile. XOR-chunk swizzle on all LDS tiles.
template<int SPLT>
__global__ __launch_bounds__(512, 4) void flash_kernel(const _Float16* __restrict__ F16,
        const _Float16* __restrict__ Vt, const float* __restrict__ csv,
        _Float16* __restrict__ po, float* __restrict__ av)
{
    constexpr int KT = NT / SPLT;
    __shared__ __align__(16) _Float16 Kb[KV * CCH];    // 16 KB
    __shared__ __align__(16) _Float16 Pb[ROWS * KV];   // 8 KB
    __shared__ float pmbuf[2][ROWS];
    __shared__ float abuf[ROWS];
    __shared__ float lpart[2][ROWS];
    __shared__ float lbuf[ROWS];

    const int tid  = threadIdx.x;
    const int wv   = tid >> 6;
    const int lane = tid & 63;
    const int g    = lane >> 4, c16 = lane & 15;
    const int rg   = wv & 3;          // QK rowgroup
    const int h    = wv >> 2;         // QK key half
    const int flat = blockIdx.x;
    const int sp   = flat % SPLT;     // same split -> same XCD (round-robin dispatch)
    const int n0   = (flat / SPLT) * ROWS;
    const int t0   = sp * KT;

    // K staging: thread covers key = tid>>3, chunks sc0, sc0+1 (16B chunks, XOR-swizzled)
    const int skey = tid >> 3;
    const int sc0  = (tid & 7) * 2;
    const int sc1  = sc0 + 1;
    const int swz0 = skey * CCH + (((sc0 & 8) | ((sc0 & 7) ^ (skey & 7))) * 8);
    const int swz1 = skey * CCH + (((sc1 & 8) | ((sc1 & 7) ^ (skey & 7))) * 8);

    // Q B-frags for rowgroup rg (column = query = n0 + rg*16 + c16)
    f16x8 q[4];
    #pragma unroll
    for (int kk = 0; kk < 4; ++kk)
        q[kk] = *(const f16x8*)(F16 + (n0 + rg * 16 + c16) * CCH + kk * 32 + g * 8);

    f32x4 o[4][4];
    #pragma unroll
    for (int rf = 0; rf < 4; ++rf)
        #pragma unroll
        for (int df = 0; df < 4; ++df) o[rf][df] = 0.0f;
    float m_run = -1e30f, l_run = 0.0f;

    const int sw = c16 & 7;                   // swizzle key for K-read / P rows
    const _Float16* vbase = Vt + (size_t)(wv * 64 + c16) * NS + g * 8;

    // prologue: stage K(t0)
    {
        const _Float16* ks = F16 + (size_t)(t0 * KV + skey) * CCH;
        *(f16x8*)(&Kb[swz0]) = *(const f16x8*)(ks + sc0 * 8);
        *(f16x8*)(&Kb[swz1]) = *(const f16x8*)(ks + sc1 * 8);
    }
    __syncthreads();

    for (int tl = 0; tl < KT; ++tl) {
        const int m0 = (t0 + tl) * KV;

        // ---- QK^T (A=K from Kb, B=q): s[cf][r] = S[key h*32+cf*16+g*4+r][query c16] ----
        f32x4 s[2];
        s[0] = 0.0f; s[1] = 0.0f;
        #pragma unroll
        for (int cf = 0; cf < 2; ++cf) {
            const _Float16* kr = &Kb[(h * 32 + cf * 16 + c16) * CCH];
            #pragma unroll
            for (int kk = 0; kk < 4; ++kk) {
                const int c  = kk * 4 + g;
                const int cc = (c & 8) | ((c & 7) ^ sw);
                s[cf] = __builtin_amdgcn_mfma_f32_16x16x32_f16(
                            *(const f16x8*)(kr + cc * 8), q[kk], s[cf], 0, 0, 0);
            }
        }

        f32x4 cs[2];
        cs[0] = *(const f32x4*)(csv + m0 + h * 32 + g * 4);
        cs[1] = *(const f32x4*)(csv + m0 + h * 32 + 16 + g * 4);

        // partial max over this wave's 32 keys (per query c16)
        float pm = -1e30f;
        #pragma unroll
        for (int cf = 0; cf < 2; ++cf)
            #pragma unroll
            for (int r = 0; r < 4; ++r)
                pm = fmaxf(pm, (cs[cf][r] > 0.0f) ? s[cf][r] * cs[cf][r] : -1e30f);
        pm = fmaxf(pm, __shfl_xor(pm, 16));
        pm = fmaxf(pm, __shfl_xor(pm, 32));
        if (g == 0) pmbuf[h][rg * 16 + c16] = pm;
        __syncthreads();   // #1: pm ready; all Kb reads done

        // K prefetch for t+1 (latency hides under softmax finish)
        f16x8 k0, k1;
        const bool havek = (tl + 1 < KT);
        if (havek) {
            const _Float16* ks = F16 + (size_t)((t0 + tl + 1) * KV + skey) * CCH;
            k0 = *(const f16x8*)(ks + sc0 * 8);
            k1 = *(const f16x8*)(ks + sc1 * 8);
        }

        // combine halves -> tile max; defer-max (identical in both h-waves of rg)
        const float tm = fmaxf(pm, pmbuf[h ^ 1][rg * 16 + c16]);
        float al = 1.0f;
        if (__any(tm > m_run + 8.0f)) {
            float nm = fmaxf(m_run, tm);
            al = __expf(m_run - nm);
            l_run *= al; m_run = nm;
        }
        if (h == 0 && g == 0) abuf[rg * 16 + c16] = al;

        // P = exp(s*cs - m) (masked 0), partial row-sum, swizzled Pb write (f16x4)
        float ps = 0.0f;
        const int prow = rg * 16 + c16;
        #pragma unroll
        for (int cf = 0; cf < 2; ++cf) {
            f16x4 ph;
            #pragma unroll
            for (int r = 0; r < 4; ++r) {
                float e = (cs[cf][r] > 0.0f) ? __expf(s[cf][r] * cs[cf][r] - m_run) : 0.0f;
                ps += e;
                ph[r] = (_Float16)e;
            }
            const int kc = h * 4 + cf * 2 + (g >> 1);
            *(f16x4*)(&Pb[prow * KV + ((kc ^ sw) * 8) + (g & 1) * 4]) = ph;
        }
        ps += __shfl_xor(ps, 16);
        ps += __shfl_xor(ps, 32);
        l_run += ps;

        if (havek) {
            *(f16x8*)(&Kb[swz0]) = k0;
            *(f16x8*)(&Kb[swz1]) = k1;
        }
        __syncthreads();   // #2: P + abuf + next K ready

        // ---- PV: O[64 rows][this wave's 64 d] ----
        {
            f32x4 a4[4];
            #pragma unroll
            for (int rf = 0; rf < 4; ++rf) a4[rf] = *(const f32x4*)(&abuf[rf * 16 + g * 4]);
            bool anyr = false;
            #pragma unroll
            for (int rf = 0; rf < 4; ++rf)
                #pragma unroll
                for (int r = 0; r < 4; ++r) anyr = anyr || (a4[rf][r] != 1.0f);
            if (__any(anyr)) {
                #pragma unroll
                for (int rf = 0; rf < 4; ++rf)
                    #pragma unroll
                    for (int df = 0; df < 4; ++df)
                        #pragma unroll
                        for (int r = 0; r < 4; ++r) o[rf][df][r] *= a4[rf][r];
            }
        }
        #pragma unroll
        for (int kf = 0; kf < 2; ++kf) {
            f16x8 pa[4];
            #pragma unroll
            for (int rf = 0; rf < 4; ++rf)
                pa[rf] = *(const f16x8*)(&Pb[(rf * 16 + c16) * KV + (((kf * 4 + g) ^ sw) * 8)]);
            const _Float16* vb = vbase + m0 + kf * 32;
            f16x8 vn = *(const f16x8*)(vb);
            #pragma unroll
            for (int df = 0; df < 4; ++df) {
                f16x8 vc = vn;
                if (df < 3) vn = *(const f16x8*)(vb + (size_t)(df + 1) * 16 * NS);
                #pragma unroll
                for (int rf = 0; rf < 4; ++rf)
                    o[rf][df] = __builtin_amdgcn_mfma_f32_16x16x32_f16(
                                    pa[rf], vc, o[rf][df], 0, 0, 0);
            }
        }
        __syncthreads();   // #3: PV's Pb/abuf reads done before next tile overwrites
    }

    // epilogue: combine per-half l, share 1/l, write normalized partial O + logsumexp
    if (g == 0) lpart[h][rg * 16 + c16] = l_run;
    __syncthreads();
    if (h == 0 && g == 0) {
        const int row = rg * 16 + c16;
        float lt = lpart[0][row] + lpart[1][row];
        lbuf[row] = (lt > 0.0f) ? 1.0f / lt : 0.0f;
        av[sp * NS + n0 + row] = (lt > 0.0f) ? m_run + __logf(lt) : -1e30f;
    }
    __syncthreads();
    #pragma unroll
    for (int rf = 0; rf < 4; ++rf) {
        f32x4 li = *(const f32x4*)(&lbuf[rf * 16 + g * 4]);
        #pragma unroll
        for (int df = 0; df < 4; ++df) {
            f16x4 res;
            #pragma unroll
            for (int r = 0; r < 4; ++r) res[r] = (_Float16)(o[rf][df][r] * li[r]);
            *(f16x4*)(po + ((size_t)sp * DV + wv * 64 + df * 16 + c16) * NS
                          + n0 + rf * 16 + g * 4) = res;
        }
    }
}

// ---------- final: merge splits (logsumexp weights) + mask blend ----------
template<int S>
__global__ __launch_bounds__(192) void combine_kernel(const float* __restrict__ x,
        const float* __restrict__ mask, const _Float16* __restrict__ po,
        const float* __restrict__ av, float* __restrict__ out)
{
    int i = blockIdx.x;      // 0..95
    int c = blockIdx.y;      // 0..127
    int w = threadIdx.x;     // 0..191
    int n = i * 96 + (w >> 1);

    float A = -1e30f;
    #pragma unroll
    for (int s = 0; s < S; ++s) A = fmaxf(A, av[s * NS + n]);
    float wt[S], wsum = 0.0f;
    #pragma unroll
    for (int s = 0; s < S; ++s) {
        float a = av[s * NS + n];
        float e = (a > -1e29f) ? __expf(a - A) : 0.0f;
        wt[s] = e; wsum += e;
    }
    float invw = (wsum > 0.0f) ? 1.0f / wsum : 0.0f;

    #pragma unroll
    for (int di = 0; di < 2; ++di) {
        int h = 2 * i + di;
        int d = c * 4 + di * 2 + (w & 1);
        float rv = 0.0f;
        #pragma unroll
        for (int s = 0; s < S; ++s)
            rv += wt[s] * (float)po[((size_t)s * DV + d) * NS + n];
        rv *= invw;
        float xv = x[c * HW + h * W_ + w];
        float mv = mask[h * W_ + w];
        out[c * HW + h * W_ + w] = xv * (1.0f - mv) + rv * mv;
    }
}

extern "C" void kernel_launch(void* const* d_in, const int* in_sizes, int n_in,
                              void* d_out, int out_size, void* d_ws, size_t ws_size,
                              hipStream_t stream) {
    const float* x    = (const float*)d_in[0];
    const float* mask = (const float*)d_in[1];
    float* out = (float*)d_out;

    char* ws = (char*)d_ws;
    _Float16* Vt  = (_Float16*)(ws);                     //  9,437,184 B
    _Float16* F16 = (_Float16*)(ws + 9437184);           //  2,359,296 B
    float*    csv = (float*)   (ws + 11796480);          //     36,864 B
    float*    av  = (float*)   (ws + 11833344);          //    294,912 B
    _Float16* po  = (_Float16*)(ws + 12128256);          //  SPL * 9,437,184 B

    prep_vt_kernel <<<dim3(36, 512), 256, 0, stream>>>(x, Vt, F16);
    prep_csv_kernel<<<NS, 64, 0, stream>>>(F16, mask, csv);

    const size_t base = 12128256ull;
    if (ws_size >= base + 8ull * 9437184ull) {
        flash_kernel<8><<<144 * 8, 512, 0, stream>>>(F16, Vt, csv, po, av);
        combine_kernel<8><<<dim3(96, 128), 192, 0, stream>>>(x, mask, po, av, out);
    } else {
        flash_kernel<4><<<144 * 4, 512, 0, stream>>>(F16, Vt, csv, po, av);
        combine_kernel<4><<<dim3(96, 128), 192, 0, stream>>>(x, mask, po, av, out);
    }
}

// Round 7
// 341.741 us; speedup vs baseline: 1.7906x; 1.0310x over previous
//
#include <hip/hip_runtime.h>
#include <hip/hip_bf16.h>

typedef _Float16 f16x8 __attribute__((ext_vector_type(8)));
typedef _Float16 f16x4 __attribute__((ext_vector_type(4)));
typedef float    f32x4 __attribute__((ext_vector_type(4)));

#define HW   36864   // 192*192
#define W_   192
#define NS   9216    // 96*96 patches
#define CCH  128     // channels (QK inner dim)
#define DV   512     // c*r*r  (PV output dim)
#define ROWS 64      // query rows per block
#define KV   64      // keys per tile
#define NT   144     // total key tiles

// ---------- prep: Vt[d][m] (f16, transposed patches) + F16[m][c] (f16 feat) ----------
__global__ __launch_bounds__(256) void prep_vt_kernel(const float* __restrict__ x,
        _Float16* __restrict__ Vt, _Float16* __restrict__ F16)
{
    int m = blockIdx.x * 256 + threadIdx.x;   // 0..9215
    int d = blockIdx.y;                       // 0..511
    int c = d >> 2, di = (d >> 1) & 1, dj = d & 1;
    int i = m / 96, j = m - i * 96;
    float v = x[c * HW + (2 * i + di) * W_ + (2 * j + dj)];
    _Float16 h = (_Float16)v;
    Vt[(size_t)d * NS + m] = h;
    if ((d & 3) == 0) F16[m * CCH + c] = h;   // di=dj=0 element == feat
}

// ---------- prep: csv[m] = valid ? 10/(||f_m||+eps) : 0 ----------
__global__ __launch_bounds__(64) void prep_csv_kernel(const _Float16* __restrict__ F16,
        const float* __restrict__ mask, float* __restrict__ csv)
{
    int m = blockIdx.x;
    int t = threadIdx.x;                      // one wave
    float a = (float)F16[m * CCH + 2 * t];
    float b = (float)F16[m * CCH + 2 * t + 1];
    float ss = a * a + b * b;
    #pragma unroll
    for (int off = 1; off <= 32; off <<= 1)
        ss += __shfl_xor(ss, off);
    if (t == 0) {
        int i = m / 96, j = m - i * 96;
        float ms = mask[(2 * i) * W_ + 2 * j];
        csv[m] = (ms == 0.0f) ? 10.0f / (sqrtf(ss) + 1e-8f) : 0.0f;
    }
}

// ---------- fused masked attention: 64 rows x 256 d, 4 waves, 1 barrier/tile ----------
// Wave wv: QK role = rowgroup wv (16 queries x all 64 keys, swapped mfma(K,Q), softmax
// fully in-wave), PV role = d-slice wv*64 (all 64 rows), V prefetched into regs at tile
// top. K double-buffered via global_load_lds (pre-swizzled src); P double-buffered.
template<int KT>
__global__ __launch_bounds__(256, 3) void flash_kernel(const _Float16* __restrict__ F16,
        const _Float16* __restrict__ Vt, const float* __restrict__ csv,
        _Float16* __restrict__ po, float* __restrict__ av)
{
    constexpr int SPLT = NT / KT;
    __shared__ __align__(16) _Float16 Kb[2][KV * CCH];   // 2 x 16 KB, [key][chunk^(key&7)]
    __shared__ __align__(16) _Float16 Pb[2][ROWS * KV];  // 2 x 8 KB,  [row][chunk^(row&7)]
    __shared__ __align__(16) float    abuf[2][ROWS];     // per-row rescale factors
    __shared__ __align__(16) int      flags[2][4];       // per-wave rescale flags
    __shared__ __align__(16) float    lbuf[ROWS];        // final 1/l

    const int tid  = threadIdx.x;
    const int wv   = tid >> 6;
    const int lane = tid & 63;
    const int g    = lane >> 4, c16 = lane & 15;
    const int flat = blockIdx.x;
    const int sp   = flat % SPLT;      // same split -> same XCD (round-robin dispatch)
    const int rest = flat / SPLT;
    const int n0   = (rest >> 1) * ROWS;
    const int d0   = (rest & 1) * 256;
    const int t0   = sp * KT;
    const int sw   = c16 & 7;

    // stage K tile t into Kb[nb]: wave covers keys wv*16..+15, pre-swizzled global src
    auto stageK = [&](int nb, int t) {
        #pragma unroll
        for (int j = 0; j < 4; ++j) {
            const int key  = wv * 16 + j * 4 + g;
            const int csrc = (c16 & 8) | ((c16 & 7) ^ (key & 7));
            __builtin_amdgcn_global_load_lds(
                (const __attribute__((address_space(1))) void*)
                    (F16 + (size_t)(t * KV + key) * CCH + csrc * 8),
                (__attribute__((address_space(3))) void*)
                    (&Kb[nb][(wv * 16 + j * 4) * CCH]),
                16, 0, 0);
        }
    };

    // Q B-frags (col = query = n0 + wv*16 + c16, k = kk*32 + g*8 + e)
    f16x8 q[4];
    #pragma unroll
    for (int kk = 0; kk < 4; ++kk)
        q[kk] = *(const f16x8*)(F16 + (n0 + wv * 16 + c16) * CCH + kk * 32 + g * 8);

    f32x4 o[4][4];
    #pragma unroll
    for (int rf = 0; rf < 4; ++rf)
        #pragma unroll
        for (int df = 0; df < 4; ++df) o[rf][df] = 0.0f;
    float m_run = -1e30f, l_run = 0.0f;

    const _Float16* vbase = Vt + (size_t)(d0 + wv * 64 + c16) * NS + g * 8;

    stageK(0, t0);
    __syncthreads();

    for (int tl = 0; tl < KT; ++tl) {
        const int buf = tl & 1;
        const int m0  = (t0 + tl) * KV;

        // ---- V prefetch for THIS tile (consumed in PV after the barrier) ----
        f16x8 vreg[8];
        #pragma unroll
        for (int kf = 0; kf < 2; ++kf)
            #pragma unroll
            for (int df = 0; df < 4; ++df)
                vreg[kf * 4 + df] = *(const f16x8*)(vbase + (size_t)(df * 16) * NS
                                                    + m0 + kf * 32);

        // ---- QK^T (A = K from Kb, B = q): s[cf][r] -> key cf*16+g*4+r, query c16 ----
        f32x4 s[4];
        #pragma unroll
        for (int cf = 0; cf < 4; ++cf) s[cf] = 0.0f;
        #pragma unroll
        for (int cf = 0; cf < 4; ++cf) {
            const _Float16* kr = &Kb[buf][(cf * 16 + c16) * CCH];
            #pragma unroll
            for (int kk = 0; kk < 4; ++kk) {
                const int c  = kk * 4 + g;
                const int cc = (c & 8) | ((c & 7) ^ sw);
                s[cf] = __builtin_amdgcn_mfma_f32_16x16x32_f16(
                            *(const f16x8*)(kr + cc * 8), q[kk], s[cf], 0, 0, 0);
            }
        }

        f32x4 cs[4];
        #pragma unroll
        for (int cf = 0; cf < 4; ++cf)
            cs[cf] = *(const f32x4*)(csv + m0 + cf * 16 + g * 4);

        // ---- softmax (self-contained: lane owns query c16; reduce over g copies) ----
        float tm = -1e30f;
        #pragma unroll
        for (int cf = 0; cf < 4; ++cf)
            #pragma unroll
            for (int r = 0; r < 4; ++r)
                tm = fmaxf(tm, (cs[cf][r] > 0.0f) ? s[cf][r] * cs[cf][r] : -1e30f);
        tm = fmaxf(tm, __shfl_xor(tm, 16));
        tm = fmaxf(tm, __shfl_xor(tm, 32));

        float al = 1.0f;
        const bool trig = __any(tm > m_run + 8.0f);
        if (trig) {
            float nm = fmaxf(m_run, tm);
            al = __expf(m_run - nm);
            l_run *= al; m_run = nm;
        }
        if (lane == 0) flags[buf][wv] = trig ? 1 : 0;
        if (g == 0)    abuf[buf][wv * 16 + c16] = al;

        // P = exp(s*cs - m) (masked -> 0), row-sum, swizzled b64 writes
        float ps = 0.0f;
        const int prow = wv * 16 + c16;
        #pragma unroll
        for (int cf = 0; cf < 4; ++cf) {
            f16x4 ph;
            #pragma unroll
            for (int r = 0; r < 4; ++r) {
                float e = (cs[cf][r] > 0.0f) ? __expf(s[cf][r] * cs[cf][r] - m_run) : 0.0f;
                ps += e;
                ph[r] = (_Float16)e;
            }
            const int ch = (cf * 2 + (g >> 1)) ^ sw;
            *(f16x4*)(&Pb[buf][prow * KV + ch * 8 + (g & 1) * 4]) = ph;
        }
        ps += __shfl_xor(ps, 16);
        ps += __shfl_xor(ps, 32);
        l_run += ps;

        // async K stage for next tile (arrives by the barrier's implicit vmcnt drain)
        if (tl + 1 < KT) stageK(buf ^ 1, t0 + tl + 1);

        __syncthreads();   // the ONLY barrier: publishes P(t), abuf/flags(t), K(t+1)

        // ---- PV: O[64 rows][this wave's 64 d] from Pb[buf] + prefetched vreg ----
        {
            const int4 fl = *(const int4*)(&flags[buf][0]);
            if (fl.x | fl.y | fl.z | fl.w) {
                #pragma unroll
                for (int rf = 0; rf < 4; ++rf) {
                    f32x4 a4 = *(const f32x4*)(&abuf[buf][rf * 16 + g * 4]);
                    #pragma unroll
                    for (int df = 0; df < 4; ++df)
                        #pragma unroll
                        for (int r = 0; r < 4; ++r) o[rf][df][r] *= a4[r];
                }
            }
        }
        #pragma unroll
        for (int kf = 0; kf < 2; ++kf) {
            f16x8 pa[4];
            #pragma unroll
            for (int rf = 0; rf < 4; ++rf)
                pa[rf] = *(const f16x8*)(&Pb[buf][(rf * 16 + c16) * KV
                                                  + (((kf * 4 + g) ^ sw) * 8)]);
            #pragma unroll
            for (int df = 0; df < 4; ++df)
                #pragma unroll
                for (int rf = 0; rf < 4; ++rf)
                    o[rf][df] = __builtin_amdgcn_mfma_f32_16x16x32_f16(
                                    pa[rf], vreg[kf * 4 + df], o[rf][df], 0, 0, 0);
        }
    }

    // epilogue: share 1/l, write normalized partial O (f16) + logsumexp
    if (g == 0) {
        lbuf[wv * 16 + c16] = (l_run > 0.0f) ? 1.0f / l_run : 0.0f;
        if (d0 == 0)
            av[sp * NS + n0 + wv * 16 + c16] =
                (l_run > 0.0f) ? m_run + __logf(l_run) : -1e30f;
    }
    __syncthreads();
    #pragma unroll
    for (int rf = 0; rf < 4; ++rf) {
        f32x4 li = *(const f32x4*)(&lbuf[rf * 16 + g * 4]);
        #pragma unroll
        for (int df = 0; df < 4; ++df) {
            f16x4 res;
            #pragma unroll
            for (int r = 0; r < 4; ++r) res[r] = (_Float16)(o[rf][df][r] * li[r]);
            *(f16x4*)(po + ((size_t)sp * DV + d0 + wv * 64 + df * 16 + c16) * NS
                          + n0 + rf * 16 + g * 4) = res;
        }
    }
}

// ---------- final: merge splits (logsumexp weights) + mask blend ----------
template<int S>
__global__ __launch_bounds__(192) void combine_kernel(const float* __restrict__ x,
        const float* __restrict__ mask, const _Float16* __restrict__ po,
        const float* __restrict__ av, float* __restrict__ out)
{
    int i = blockIdx.x;      // 0..95
    int c = blockIdx.y;      // 0..127
    int w = threadIdx.x;     // 0..191
    int n = i * 96 + (w >> 1);

    float A = -1e30f;
    #pragma unroll
    for (int s = 0; s < S; ++s) A = fmaxf(A, av[s * NS + n]);
    float wt[S], wsum = 0.0f;
    #pragma unroll
    for (int s = 0; s < S; ++s) {
        float a = av[s * NS + n];
        float e = (a > -1e29f) ? __expf(a - A) : 0.0f;
        wt[s] = e; wsum += e;
    }
    float invw = (wsum > 0.0f) ? 1.0f / wsum : 0.0f;

    #pragma unroll
    for (int di = 0; di < 2; ++di) {
        int h = 2 * i + di;
        int d = c * 4 + di * 2 + (w & 1);
        float rv = 0.0f;
        #pragma unroll
        for (int s = 0; s < S; ++s)
            rv += wt[s] * (float)po[((size_t)s * DV + d) * NS + n];
        rv *= invw;
        float xv = x[c * HW + h * W_ + w];
        float mv = mask[h * W_ + w];
        out[c * HW + h * W_ + w] = xv * (1.0f - mv) + rv * mv;
    }
}

extern "C" void kernel_launch(void* const* d_in, const int* in_sizes, int n_in,
                              void* d_out, int out_size, void* d_ws, size_t ws_size,
                              hipStream_t stream) {
    const float* x    = (const float*)d_in[0];
    const float* mask = (const float*)d_in[1];
    float* out = (float*)d_out;

    char* ws = (char*)d_ws;
    _Float16* Vt  = (_Float16*)(ws);                     //  9,437,184 B
    _Float16* F16 = (_Float16*)(ws + 9437184);           //  2,359,296 B
    float*    csv = (float*)   (ws + 11796480);          //     36,864 B
    float*    av  = (float*)   (ws + 11833344);          //    294,912 B
    _Float16* po  = (_Float16*)(ws + 12128256);          //  SPL * 9,437,184 B

    prep_vt_kernel <<<dim3(36, 512), 256, 0, stream>>>(x, Vt, F16);
    prep_csv_kernel<<<NS, 64, 0, stream>>>(F16, mask, csv);

    const size_t base = 12128256ull;
    if (ws_size >= base + 8ull * 9437184ull) {
        flash_kernel<18><<<288 * 8, 256, 0, stream>>>(F16, Vt, csv, po, av);
        combine_kernel<8><<<dim3(96, 128), 192, 0, stream>>>(x, mask, po, av, out);
    } else {
        flash_kernel<36><<<288 * 4, 256, 0, stream>>>(F16, Vt, csv, po, av);
        combine_kernel<4><<<dim3(96, 128), 192, 0, stream>>>(x, mask, po, av, out);
    }
}